// Round 5
// baseline (538.510 us; speedup 1.0000x reference)
//
#include <hip/hip_runtime.h>
#include <hip/hip_bf16.h>

// ---------------------------------------------------------------------------
// VersorAttention on MI355X (gfx950).
// cast x->bf16; per projection {buildW, m97-style GEMM with fused normalize
// epilogue (Q: sig*scale*log2e; V: transposed write)}; flash attention v3
// (4 waves x 32 q-rows, KV=64, K/V double-buffered in LDS via global_load_lds
// with XOR-swizzle, ONE barrier per tile, defer-max, exp2); final GEMM with
// fused fp32 normalize -> d_out.
// R4 fix: K stage-side swizzle must use the ABSOLUTE tile row (kr&7), not the
// row-within-chunk (lane>>5 = row&1).  Read side is (row&7)<<3; both sides
// must match (rule #21).  V chunks are 8 rows tall so vrow_l == row&7 already.
// ---------------------------------------------------------------------------

typedef unsigned short u16;
typedef unsigned short u16x8 __attribute__((ext_vector_type(8)));
typedef unsigned short u16x4 __attribute__((ext_vector_type(4)));
typedef short          s16x8 __attribute__((ext_vector_type(8)));
typedef float          f32x4 __attribute__((ext_vector_type(4)));

#define B_DIM 2
#define S_DIM 2048
#define D_DIM 64
#define NH    8
#define HD    256          // head feature = (D/NH)*32
#define F_DIM 2048         // D*32
#define TOK   4096         // B*S

// blade lane ordering: sorted by (grade, mask)
__constant__ int LANE_MASK[32] = {
    0,
    1, 2, 4, 8, 16,
    3, 5, 6, 9, 10, 12, 17, 18, 20, 24,
    7, 11, 13, 14, 19, 21, 22, 25, 26, 28,
    15, 23, 27, 29, 30,
    31};
__constant__ int MASK_LANE[32] = {
    0, 1, 2, 6, 3, 7, 8, 16, 4, 9, 10, 17, 11, 18, 19, 26,
    5, 12, 13, 20, 14, 21, 22, 27, 15, 23, 24, 28, 25, 29, 30, 31};

__device__ __forceinline__ float gp_sign(int a, int b) {
  int swaps = 0;
  int aa = a >> 1;
  while (aa) { swaps += __popc(aa & b); aa >>= 1; }
  float s = (swaps & 1) ? -1.0f : 1.0f;
  if (a & b & 16) s = -s;   // e5*e5 = -1 (bit 4); e1..e4 square to +1
  return s;
}

__device__ __forceinline__ u16 f2bf(float f) {
  unsigned u = __float_as_uint(f);
  u += 0x7fffu + ((u >> 16) & 1u);   // round-to-nearest-even
  return (u16)(u >> 16);
}

__device__ __forceinline__ f32x4 mfma16(s16x8 a, s16x8 b, f32x4 c) {
  return __builtin_amdgcn_mfma_f32_16x16x32_bf16(a, b, c, 0, 0, 0);
}

// async global->LDS, 16B per lane; LDS dest = wave-uniform base + lane*16
__device__ __forceinline__ void gload16(const u16* g, u16* l) {
  __builtin_amdgcn_global_load_lds(
      (const __attribute__((address_space(1))) void*)g,
      (__attribute__((address_space(3))) void*)l, 16, 0, 0);
}

// ---------------------------------------------------------------------------
// x (fp32) -> bf16
__global__ __launch_bounds__(256) void k_cast(const float* __restrict__ x,
                                              u16* __restrict__ xb) {
  int i = blockIdx.x * 256 + threadIdx.x;   // 8 elements each
  const float4* x4 = (const float4*)x;
  float4 a = x4[2 * i], b = x4[2 * i + 1];
  u16x8 r;
  r[0] = f2bf(a.x); r[1] = f2bf(a.y); r[2] = f2bf(a.z); r[3] = f2bf(a.w);
  r[4] = f2bf(b.x); r[5] = f2bf(b.y); r[6] = f2bf(b.z); r[7] = f2bf(b.w);
  *(u16x8*)&xb[8 * i] = r;
}

// ---------------------------------------------------------------------------
// W[(o*32+k)*2048 + i*32+l] = gp_sign(mask_k^mask_l, mask_l) * w[o,i,j],
// mask_j = mask_k ^ mask_l  (gp table one-hot in output blade).
__global__ __launch_bounds__(256) void k_buildw(const float* __restrict__ w,
                                                u16* __restrict__ W) {
  __shared__ float wvals[32];
  __shared__ int   jt[1024];
  __shared__ float st[1024];
  const int o = blockIdx.x >> 6, i = blockIdx.x & 63;
  const int tid = threadIdx.x;
  for (int e = tid; e < 1024; e += 256) {
    int k = e >> 5, l = e & 31;
    int mk = LANE_MASK[k], ml = LANE_MASK[l];
    int mj = mk ^ ml;
    jt[e] = MASK_LANE[mj];
    st[e] = gp_sign(mj, ml);
  }
  if (tid < 32) wvals[tid] = w[(o * D_DIM + i) * 32 + tid];
  __syncthreads();
  for (int e = tid; e < 1024; e += 256) {
    int k = e >> 5, l = e & 31;
    size_t off = (size_t)(o * 32 + k) * F_DIM + i * 32 + l;
    W[off] = f2bf(st[e] * wvals[jt[e]]);
  }
}

// ---------------------------------------------------------------------------
// C(MxN) = A(MxK) . B(NxK)^T  with fused multivector-normalize epilogue.
// m97 structure: 128x128 tile, BK=64, linear LDS, global_load_lds width=16.
// MODE 0: bf16 out.  MODE 1: bf16 out * sig*scale*log2e (Q).
// MODE 2: fp32 out (final).  MODE 3: bf16 transposed out (V -> Vt[b][f][s]).
template <int MODE>
__global__ __launch_bounds__(256) void k_gemm_fused(const u16* __restrict__ A,
                                                    const u16* __restrict__ B,
                                                    u16* __restrict__ outb,
                                                    float* __restrict__ outf) {
  constexpr int K = F_DIM, N = F_DIM;
  __shared__ u16 As[128 * 64];
  __shared__ u16 Bs[128 * 64];
  const int tid = threadIdx.x;
  const int wid = tid >> 6, lane = tid & 63;
  const int row0 = blockIdx.y * 128, col0 = blockIdx.x * 128;
  const int wm = (wid >> 1) * 64, wn = (wid & 1) * 64;
  const int lr = lane & 15, lk = (lane >> 4) * 8;
  const int srow = lane >> 3, scol = (lane & 7) * 8;   // staging: 8 rows/wave

  f32x4 acc[4][4];
#pragma unroll
  for (int m = 0; m < 4; ++m)
#pragma unroll
    for (int n = 0; n < 4; ++n) acc[m][n] = (f32x4)0.0f;

  for (int k0 = 0; k0 < K; k0 += 64) {
#pragma unroll
    for (int it = 0; it < 4; ++it) {
      int c = it * 4 + wid;            // 16 chunks of 8 rows x 64 cols
      gload16(&A[(size_t)(row0 + c * 8 + srow) * K + k0 + scol], &As[c * 512]);
      gload16(&B[(size_t)(col0 + c * 8 + srow) * K + k0 + scol], &Bs[c * 512]);
    }
    __syncthreads();
#pragma unroll
    for (int ks = 0; ks < 64; ks += 32) {
      s16x8 af[4], bf[4];
#pragma unroll
      for (int m = 0; m < 4; ++m)
        af[m] = *(const s16x8*)&As[(wm + m * 16 + lr) * 64 + ks + lk];
#pragma unroll
      for (int n = 0; n < 4; ++n)
        bf[n] = *(const s16x8*)&Bs[(wn + n * 16 + lr) * 64 + ks + lk];
#pragma unroll
      for (int m = 0; m < 4; ++m)
#pragma unroll
        for (int n = 0; n < 4; ++n)
          acc[m][n] = mfma16(af[m], bf[n], acc[m][n]);
    }
    __syncthreads();
  }

  // epilogue: normalize each 32-lane multivector (cols [c32, c32+32) of a row)
  float sc0 = 1.0f, sc1 = 1.0f;
  if (MODE == 1) {
    const float qs = 0.35355339059327373f * 1.4426950408889634f;  // 1/sqrt(8)*log2e
    int m0 = LANE_MASK[lr], m1 = LANE_MASK[16 + lr];
    sc0 = gp_sign(m0, m0) * qs;
    sc1 = gp_sign(m1, m1) * qs;
  }
#pragma unroll
  for (int m = 0; m < 4; ++m) {
    int rowb = row0 + wm + m * 16 + (lane >> 4) * 4;
#pragma unroll
    for (int np = 0; np < 2; ++np) {
      int n0 = 2 * np, n1 = n0 + 1;
      int colb = col0 + wn + np * 32 + lr;
      f32x4 inv;
#pragma unroll
      for (int r = 0; r < 4; ++r) {
        float a0 = acc[m][n0][r], a1 = acc[m][n1][r];
        float s2 = a0 * a0 + a1 * a1;
        s2 += __shfl_xor(s2, 1);
        s2 += __shfl_xor(s2, 2);
        s2 += __shfl_xor(s2, 4);
        s2 += __shfl_xor(s2, 8);
        inv[r] = 1.0f / sqrtf(s2 + 1e-6f);
      }
      if (MODE == 3) {
        // V: write normalized, transposed: Vt[(b*F + f)*S + s]
        int bb = rowb >> 11, s0 = rowb & 2047;
        u16x4 p0, p1;
#pragma unroll
        for (int r = 0; r < 4; ++r) {
          p0[r] = f2bf(acc[m][n0][r] * inv[r]);
          p1[r] = f2bf(acc[m][n1][r] * inv[r]);
        }
        *(u16x4*)&outb[((size_t)bb * F_DIM + colb) * S_DIM + s0] = p0;
        *(u16x4*)&outb[((size_t)bb * F_DIM + colb + 16) * S_DIM + s0] = p1;
      } else {
#pragma unroll
        for (int r = 0; r < 4; ++r) {
          size_t o = (size_t)(rowb + r) * N + colb;
          if (MODE == 2) {
            outf[o]      = acc[m][n0][r] * inv[r];
            outf[o + 16] = acc[m][n1][r] * inv[r];
          } else {
            outb[o]      = f2bf(acc[m][n0][r] * inv[r] * sc0);
            outb[o + 16] = f2bf(acc[m][n1][r] * inv[r] * sc1);
          }
        }
      }
    }
  }
}

// ---------------------------------------------------------------------------
// Flash attention v3.  Block = 4 waves x 32 q-rows = 128 q; grid 256 (1/CU).
// KV-tile 64.  K/V double-buffered in LDS via global_load_lds (linear layout
// + XOR swizzle: byte_in_row ^= (row&7)<<4, applied on the global SOURCE at
// stage time and on the LDS address at read time -- rule #21 both-sides).
// ONE barrier per tile: issue t+1 loads, compute t, barrier (drains vmcnt).
// Scores in log2 domain (log2e folded into Q);  defer-max THR=8.
__global__ __launch_bounds__(256, 1) void k_attn(const u16* __restrict__ qb,
                                                 const u16* __restrict__ kb,
                                                 const u16* __restrict__ vt,
                                                 u16* __restrict__ ao) {
  __shared__ u16 Kbuf[2][64 * 256];   // [kv][feat], swizzled, 2x32 KB
  __shared__ u16 Vbuf[2][256 * 64];   // [feat][kv], swizzled, 2x32 KB
  __shared__ u16 Ps[4][32][72];       // per-wave P, padded pitch (18 KB)
  const int tid = threadIdx.x, wid = tid >> 6, lane = tid & 63;
  // XCD remap: 2 (b,h) pairs per XCD -> K+V (4 MB) resident in one L2
  const int rid = (blockIdx.x & 7) * 32 + (blockIdx.x >> 3);
  const int qblk = rid & 15, bh = rid >> 4;
  const int b = bh >> 3, h = bh & 7;
  const int lr = lane & 15, hi = lane >> 4;      // frag row / k-group
  const int lr7s = (lr & 7) << 3;                // read-side XOR (u16 units)
  const int q0 = qblk * 128 + wid * 32;

  // staging geometry (per wave, per tile: 8 K chunks + 8 V chunks of 1 KB)
  const int krow_l = lane >> 5;                   // 0..1 within 2-row chunk
  const int kcolb  = (lane & 31) * 8;             // linear dest col (u16)
  const int vrow_l = lane >> 3;                   // 0..7 within 8-row chunk
  const int vcol_l = ((lane & 7) * 8) ^ ((vrow_l & 7) << 3);  // vr&7==vrow_l

  // Q fragments: 2 row-frags x 8 k-chunks (sig, 1/sqrt(hd), log2e pre-folded)
  u16x8 qf[2][8];
#pragma unroll
  for (int m = 0; m < 2; ++m)
#pragma unroll
    for (int c = 0; c < 8; ++c)
      qf[m][c] = *(const u16x8*)&qb[(size_t)(b * S_DIM + q0 + m * 16 + lr) * F_DIM +
                                    h * HD + c * 32 + hi * 8];

  float mrow[2][4], lacc[2][4];
#pragma unroll
  for (int m = 0; m < 2; ++m)
#pragma unroll
    for (int r = 0; r < 4; ++r) { mrow[m][r] = -1e30f; lacc[m][r] = 0.0f; }
  f32x4 oacc[2][16];
#pragma unroll
  for (int m = 0; m < 2; ++m)
#pragma unroll
    for (int d = 0; d < 16; ++d) oacc[m][d] = (f32x4)0.0f;

  const u16* kbase = kb + (size_t)b * S_DIM * F_DIM + h * HD;
  const u16* vbase = vt + ((size_t)b * F_DIM + h * HD) * S_DIM;

  // ---- stage tile 0 into buffer 0
#pragma unroll
  for (int i = 0; i < 8; ++i) {
    int ck = wid * 8 + i;
    int kr = ck * 2 + krow_l;
    gload16(kbase + (size_t)kr * F_DIM + (kcolb ^ ((kr & 7) << 3)),
            &Kbuf[0][ck * 512]);
    int vr = ck * 8 + vrow_l;
    gload16(vbase + (size_t)vr * S_DIM + vcol_l, &Vbuf[0][ck * 512]);
  }
  __syncthreads();   // compiler emits vmcnt(0) drain here

  for (int t = 0; t < 32; ++t) {
    const int cur = t & 1;
    // ---- issue next tile's loads into the other buffer (async)
    if (t < 31) {
      int kv1 = (t + 1) * 64;
#pragma unroll
      for (int i = 0; i < 8; ++i) {
        int ck = wid * 8 + i;
        int kr = ck * 2 + krow_l;
        gload16(kbase + (size_t)(kv1 + kr) * F_DIM + (kcolb ^ ((kr & 7) << 3)),
                &Kbuf[cur ^ 1][ck * 512]);
        int vr = ck * 8 + vrow_l;
        gload16(vbase + (size_t)vr * S_DIM + kv1 + vcol_l,
                &Vbuf[cur ^ 1][ck * 512]);
      }
    }

    // ---- S = Q . K^T : 32 rows x 64 cols
    f32x4 sacc[2][4];
#pragma unroll
    for (int m = 0; m < 2; ++m)
#pragma unroll
      for (int n = 0; n < 4; ++n) sacc[m][n] = (f32x4)0.0f;
#pragma unroll
    for (int c = 0; c < 8; ++c) {
      s16x8 kf[4];
#pragma unroll
      for (int n = 0; n < 4; ++n)
        kf[n] = *(const s16x8*)&Kbuf[cur][(n * 16 + lr) * 256 +
                                          ((c * 32 + hi * 8) ^ lr7s)];
#pragma unroll
      for (int m = 0; m < 2; ++m) {
        s16x8 a = *(const s16x8*)&qf[m][c];
#pragma unroll
        for (int n = 0; n < 4; ++n) sacc[m][n] = mfma16(a, kf[n], sacc[m][n]);
      }
    }

    // ---- online softmax (log2 domain); rows = m*16 + hi*4 + r
    float pmax[2][4], need = 0.0f;
#pragma unroll
    for (int m = 0; m < 2; ++m)
#pragma unroll
      for (int r = 0; r < 4; ++r) {
        float mx = fmaxf(fmaxf(sacc[m][0][r], sacc[m][1][r]),
                         fmaxf(sacc[m][2][r], sacc[m][3][r]));
        mx = fmaxf(mx, __shfl_xor(mx, 1));
        mx = fmaxf(mx, __shfl_xor(mx, 2));
        mx = fmaxf(mx, __shfl_xor(mx, 4));
        mx = fmaxf(mx, __shfl_xor(mx, 8));
        pmax[m][r] = mx;
        need = fmaxf(need, mx - mrow[m][r]);
      }
    if (!__all(need <= 8.0f)) {
#pragma unroll
      for (int m = 0; m < 2; ++m)
#pragma unroll
        for (int r = 0; r < 4; ++r) {
          float mnew = fmaxf(mrow[m][r], pmax[m][r]);
          float alpha = exp2f(mrow[m][r] - mnew);
          mrow[m][r] = mnew;
          lacc[m][r] *= alpha;
#pragma unroll
          for (int d = 0; d < 16; ++d) oacc[m][d][r] *= alpha;
        }
    }
#pragma unroll
    for (int m = 0; m < 2; ++m)
#pragma unroll
      for (int n = 0; n < 4; ++n)
#pragma unroll
        for (int r = 0; r < 4; ++r) {
          float p = exp2f(sacc[m][n][r] - mrow[m][r]);
          lacc[m][r] += p;
          Ps[wid][m * 16 + hi * 4 + r][n * 16 + lr] = f2bf(p);
        }

    // ---- O += P . V  (per-wave LDS round-trip for P; V swizzled reads)
#pragma unroll
    for (int ks = 0; ks < 2; ++ks) {
      s16x8 pf0 = *(const s16x8*)&Ps[wid][lr][ks * 32 + hi * 8];
      s16x8 pf1 = *(const s16x8*)&Ps[wid][16 + lr][ks * 32 + hi * 8];
#pragma unroll
      for (int d0 = 0; d0 < 16; ++d0) {
        s16x8 vf = *(const s16x8*)&Vbuf[cur][(d0 * 16 + lr) * 64 +
                                             ((ks * 32 + hi * 8) ^ lr7s)];
        oacc[0][d0] = mfma16(pf0, vf, oacc[0][d0]);
        oacc[1][d0] = mfma16(pf1, vf, oacc[1][d0]);
      }
    }
    __syncthreads();   // drains this wave's prefetch (vmcnt 0) + buf swap
  }

  // ---- epilogue: reduce distributed row-sums, divide, write bf16
#pragma unroll
  for (int m = 0; m < 2; ++m)
#pragma unroll
    for (int r = 0; r < 4; ++r) {
      float s = lacc[m][r];
      s += __shfl_xor(s, 1);
      s += __shfl_xor(s, 2);
      s += __shfl_xor(s, 4);
      s += __shfl_xor(s, 8);
      float inv = 1.0f / s;
      int row = q0 + m * 16 + hi * 4 + r;
#pragma unroll
      for (int d0 = 0; d0 < 16; ++d0)
        ao[(size_t)(b * S_DIM + row) * F_DIM + h * HD + d0 * 16 + lr] =
            f2bf(oacc[m][d0][r] * inv);
    }
}

// ---------------------------------------------------------------------------
extern "C" void kernel_launch(void* const* d_in, const int* in_sizes, int n_in,
                              void* d_out, int out_size, void* d_ws, size_t ws_size,
                              hipStream_t stream) {
  const float* x  = (const float*)d_in[0];
  const float* wq = (const float*)d_in[1];
  const float* wk = (const float*)d_in[2];
  const float* wv = (const float*)d_in[3];
  const float* wo = (const float*)d_in[4];

  char* ws = (char*)d_ws;
  const size_t SZ_XB = (size_t)TOK * F_DIM * sizeof(u16);    // 16 MiB
  const size_t SZ_W  = (size_t)F_DIM * F_DIM * sizeof(u16);  // 8 MiB
  u16* Xb = (u16*)(ws);
  u16* Wb = (u16*)(ws + SZ_XB);            // reused per projection
  u16* Qb = (u16*)(ws + SZ_XB + SZ_W);
  u16* Kb = Qb + (size_t)TOK * F_DIM;
  u16* Vt = Kb + (size_t)TOK * F_DIM;      // V, normalized + transposed
  u16* Ao = Xb;                            // aliases Xb (dead after V GEMM)

  dim3 gemm_grid(F_DIM / 128, TOK / 128);  // (16, 32)
  const int bw_blocks = D_DIM * D_DIM;

  k_cast<<<TOK * F_DIM / (256 * 8), 256, 0, stream>>>(x, Xb);

  k_buildw<<<bw_blocks, 256, 0, stream>>>(wq, Wb);
  k_gemm_fused<1><<<gemm_grid, 256, 0, stream>>>(Xb, Wb, Qb, nullptr);

  k_buildw<<<bw_blocks, 256, 0, stream>>>(wk, Wb);
  k_gemm_fused<0><<<gemm_grid, 256, 0, stream>>>(Xb, Wb, Kb, nullptr);

  k_buildw<<<bw_blocks, 256, 0, stream>>>(wv, Wb);
  k_gemm_fused<3><<<gemm_grid, 256, 0, stream>>>(Xb, Wb, Vt, nullptr);

  k_attn<<<B_DIM * NH * (S_DIM / 128), 256, 0, stream>>>(Qb, Kb, Vt, Ao);

  k_buildw<<<bw_blocks, 256, 0, stream>>>(wo, Wb);
  k_gemm_fused<2><<<gemm_grid, 256, 0, stream>>>(Ao, Wb, nullptr, (float*)d_out);
}

// Round 8
// 444.020 us; speedup vs baseline: 1.2128x; 1.2128x over previous
//
#include <hip/hip_runtime.h>
#include <hip/hip_bf16.h>

// ---------------------------------------------------------------------------
// VersorAttention on MI355X (gfx950).
// cast x->bf16; per projection {buildW, m97-style GEMM with fused normalize
// epilogue (Q: sig*scale*log2e; V: transposed write)}; flash attention v4
// (8 waves x 16 q-rows = 512 thr, 2 waves/SIMD for MFMA/VALU cross-wave
// overlap, KV=64, K/V double-buffered via global_load_lds + XOR swizzle,
// ONE barrier per tile, defer-max, exp2); final GEMM + fp32 normalize.
// R6 audit fix: 8-wave staging must issue 4 K-chunks + 4 V-chunks per wave
// (ck = wid*4+i, i<4 -> 32 chunks = full 64-row K / 256-row V tile); the
// previous wid*2+i staged only half the tile.
// ---------------------------------------------------------------------------

typedef unsigned short u16;
typedef unsigned short u16x8 __attribute__((ext_vector_type(8)));
typedef unsigned short u16x4 __attribute__((ext_vector_type(4)));
typedef short          s16x8 __attribute__((ext_vector_type(8)));
typedef float          f32x4 __attribute__((ext_vector_type(4)));

#define B_DIM 2
#define S_DIM 2048
#define D_DIM 64
#define NH    8
#define HD    256          // head feature = (D/NH)*32
#define F_DIM 2048         // D*32
#define TOK   4096         // B*S

// blade lane ordering: sorted by (grade, mask)
__constant__ int LANE_MASK[32] = {
    0,
    1, 2, 4, 8, 16,
    3, 5, 6, 9, 10, 12, 17, 18, 20, 24,
    7, 11, 13, 14, 19, 21, 22, 25, 26, 28,
    15, 23, 27, 29, 30,
    31};
__constant__ int MASK_LANE[32] = {
    0, 1, 2, 6, 3, 7, 8, 16, 4, 9, 10, 17, 11, 18, 19, 26,
    5, 12, 13, 20, 14, 21, 22, 27, 15, 23, 24, 28, 25, 29, 30, 31};

__device__ __forceinline__ float gp_sign(int a, int b) {
  int swaps = 0;
  int aa = a >> 1;
  while (aa) { swaps += __popc(aa & b); aa >>= 1; }
  float s = (swaps & 1) ? -1.0f : 1.0f;
  if (a & b & 16) s = -s;   // e5*e5 = -1 (bit 4); e1..e4 square to +1
  return s;
}

__device__ __forceinline__ u16 f2bf(float f) {
  unsigned u = __float_as_uint(f);
  u += 0x7fffu + ((u >> 16) & 1u);   // round-to-nearest-even
  return (u16)(u >> 16);
}

__device__ __forceinline__ f32x4 mfma16(s16x8 a, s16x8 b, f32x4 c) {
  return __builtin_amdgcn_mfma_f32_16x16x32_bf16(a, b, c, 0, 0, 0);
}

// async global->LDS, 16B per lane; LDS dest = wave-uniform base + lane*16
__device__ __forceinline__ void gload16(const u16* g, u16* l) {
  __builtin_amdgcn_global_load_lds(
      (const __attribute__((address_space(1))) void*)g,
      (__attribute__((address_space(3))) void*)l, 16, 0, 0);
}

// ---------------------------------------------------------------------------
// x (fp32) -> bf16
__global__ __launch_bounds__(256) void k_cast(const float* __restrict__ x,
                                              u16* __restrict__ xb) {
  int i = blockIdx.x * 256 + threadIdx.x;   // 8 elements each
  const float4* x4 = (const float4*)x;
  float4 a = x4[2 * i], b = x4[2 * i + 1];
  u16x8 r;
  r[0] = f2bf(a.x); r[1] = f2bf(a.y); r[2] = f2bf(a.z); r[3] = f2bf(a.w);
  r[4] = f2bf(b.x); r[5] = f2bf(b.y); r[6] = f2bf(b.z); r[7] = f2bf(b.w);
  *(u16x8*)&xb[8 * i] = r;
}

// ---------------------------------------------------------------------------
// W[(o*32+k)*2048 + i*32+l] = gp_sign(mask_k^mask_l, mask_l) * w[o,i,j],
// mask_j = mask_k ^ mask_l  (gp table one-hot in output blade).
__global__ __launch_bounds__(256) void k_buildw(const float* __restrict__ w,
                                                u16* __restrict__ W) {
  __shared__ float wvals[32];
  __shared__ int   jt[1024];
  __shared__ float st[1024];
  const int o = blockIdx.x >> 6, i = blockIdx.x & 63;
  const int tid = threadIdx.x;
  for (int e = tid; e < 1024; e += 256) {
    int k = e >> 5, l = e & 31;
    int mk = LANE_MASK[k], ml = LANE_MASK[l];
    int mj = mk ^ ml;
    jt[e] = MASK_LANE[mj];
    st[e] = gp_sign(mj, ml);
  }
  if (tid < 32) wvals[tid] = w[(o * D_DIM + i) * 32 + tid];
  __syncthreads();
  for (int e = tid; e < 1024; e += 256) {
    int k = e >> 5, l = e & 31;
    size_t off = (size_t)(o * 32 + k) * F_DIM + i * 32 + l;
    W[off] = f2bf(st[e] * wvals[jt[e]]);
  }
}

// ---------------------------------------------------------------------------
// C(MxN) = A(MxK) . B(NxK)^T  with fused multivector-normalize epilogue.
// m97 structure: 128x128 tile, BK=64, linear LDS, global_load_lds width=16.
// MODE 0: bf16 out.  MODE 1: bf16 out * sig*scale*log2e (Q).
// MODE 2: fp32 out (final).  MODE 3: bf16 transposed out (V -> Vt[b][f][s]).
template <int MODE>
__global__ __launch_bounds__(256) void k_gemm_fused(const u16* __restrict__ A,
                                                    const u16* __restrict__ B,
                                                    u16* __restrict__ outb,
                                                    float* __restrict__ outf) {
  constexpr int K = F_DIM, N = F_DIM;
  __shared__ u16 As[128 * 64];
  __shared__ u16 Bs[128 * 64];
  const int tid = threadIdx.x;
  const int wid = tid >> 6, lane = tid & 63;
  const int row0 = blockIdx.y * 128, col0 = blockIdx.x * 128;
  const int wm = (wid >> 1) * 64, wn = (wid & 1) * 64;
  const int lr = lane & 15, lk = (lane >> 4) * 8;
  const int srow = lane >> 3, scol = (lane & 7) * 8;   // staging: 8 rows/wave

  f32x4 acc[4][4];
#pragma unroll
  for (int m = 0; m < 4; ++m)
#pragma unroll
    for (int n = 0; n < 4; ++n) acc[m][n] = (f32x4)0.0f;

  for (int k0 = 0; k0 < K; k0 += 64) {
#pragma unroll
    for (int it = 0; it < 4; ++it) {
      int c = it * 4 + wid;            // 16 chunks of 8 rows x 64 cols
      gload16(&A[(size_t)(row0 + c * 8 + srow) * K + k0 + scol], &As[c * 512]);
      gload16(&B[(size_t)(col0 + c * 8 + srow) * K + k0 + scol], &Bs[c * 512]);
    }
    __syncthreads();
#pragma unroll
    for (int ks = 0; ks < 64; ks += 32) {
      s16x8 af[4], bf[4];
#pragma unroll
      for (int m = 0; m < 4; ++m)
        af[m] = *(const s16x8*)&As[(wm + m * 16 + lr) * 64 + ks + lk];
#pragma unroll
      for (int n = 0; n < 4; ++n)
        bf[n] = *(const s16x8*)&Bs[(wn + n * 16 + lr) * 64 + ks + lk];
#pragma unroll
      for (int m = 0; m < 4; ++m)
#pragma unroll
        for (int n = 0; n < 4; ++n)
          acc[m][n] = mfma16(af[m], bf[n], acc[m][n]);
    }
    __syncthreads();
  }

  // epilogue: normalize each 32-lane multivector (cols [c32, c32+32) of a row)
  float sc0 = 1.0f, sc1 = 1.0f;
  if (MODE == 1) {
    const float qs = 0.35355339059327373f * 1.4426950408889634f;  // 1/sqrt(8)*log2e
    int m0 = LANE_MASK[lr], m1 = LANE_MASK[16 + lr];
    sc0 = gp_sign(m0, m0) * qs;
    sc1 = gp_sign(m1, m1) * qs;
  }
#pragma unroll
  for (int m = 0; m < 4; ++m) {
    int rowb = row0 + wm + m * 16 + (lane >> 4) * 4;
#pragma unroll
    for (int np = 0; np < 2; ++np) {
      int n0 = 2 * np, n1 = n0 + 1;
      int colb = col0 + wn + np * 32 + lr;
      f32x4 inv;
#pragma unroll
      for (int r = 0; r < 4; ++r) {
        float a0 = acc[m][n0][r], a1 = acc[m][n1][r];
        float s2 = a0 * a0 + a1 * a1;
        s2 += __shfl_xor(s2, 1);
        s2 += __shfl_xor(s2, 2);
        s2 += __shfl_xor(s2, 4);
        s2 += __shfl_xor(s2, 8);
        inv[r] = 1.0f / sqrtf(s2 + 1e-6f);
      }
      if (MODE == 3) {
        // V: write normalized, transposed: Vt[(b*F + f)*S + s]
        int bb = rowb >> 11, s0 = rowb & 2047;
        u16x4 p0, p1;
#pragma unroll
        for (int r = 0; r < 4; ++r) {
          p0[r] = f2bf(acc[m][n0][r] * inv[r]);
          p1[r] = f2bf(acc[m][n1][r] * inv[r]);
        }
        *(u16x4*)&outb[((size_t)bb * F_DIM + colb) * S_DIM + s0] = p0;
        *(u16x4*)&outb[((size_t)bb * F_DIM + colb + 16) * S_DIM + s0] = p1;
      } else {
#pragma unroll
        for (int r = 0; r < 4; ++r) {
          size_t o = (size_t)(rowb + r) * N + colb;
          if (MODE == 2) {
            outf[o]      = acc[m][n0][r] * inv[r];
            outf[o + 16] = acc[m][n1][r] * inv[r];
          } else {
            outb[o]      = f2bf(acc[m][n0][r] * inv[r] * sc0);
            outb[o + 16] = f2bf(acc[m][n1][r] * inv[r] * sc1);
          }
        }
      }
    }
  }
}

// ---------------------------------------------------------------------------
// Flash attention v4.  512 threads = 8 waves x 16 q-rows (q-tile 128);
// grid 256 = 1 block/CU but 2 waves/SIMD -> cross-wave MFMA/VALU overlap.
// KV=64 double-buffered via global_load_lds, XOR swizzle (stage side uses
// absolute row: kr&7 / vr&7; read side lr&7 -- rule #21 both-sides).
// ONE barrier per tile.  Scores in log2 domain; defer-max THR=8.
__global__ __launch_bounds__(512, 2) void k_attn(const u16* __restrict__ qb,
                                                 const u16* __restrict__ kb,
                                                 const u16* __restrict__ vt,
                                                 u16* __restrict__ ao) {
  __shared__ u16 Kbuf[2][64 * 256];   // [kv][feat], swizzled, 2x32 KB
  __shared__ u16 Vbuf[2][256 * 64];   // [feat][kv], swizzled, 2x32 KB
  __shared__ u16 Ps[8][16][72];       // per-wave P, padded pitch (18 KB)
  const int tid = threadIdx.x, wid = tid >> 6, lane = tid & 63;
  // XCD remap: 2 (b,h) pairs per XCD -> K+V (4 MB) resident in one L2
  const int rid = (blockIdx.x & 7) * 32 + (blockIdx.x >> 3);
  const int qblk = rid & 15, bh = rid >> 4;
  const int b = bh >> 3, h = bh & 7;
  const int lr = lane & 15, hi = lane >> 4;      // frag row / k-group
  const int lr7s = (lr & 7) << 3;                // read-side XOR (u16 units)
  const int q0 = qblk * 128 + wid * 16;

  // staging geometry: 32 K-chunks + 32 V-chunks of 1 KB, 4+4 per wave
  const int krow_l = lane >> 5;                   // 0..1 within 2-row chunk
  const int kcolb  = (lane & 31) * 8;             // linear dest col (u16)
  const int vrow_l = lane >> 3;                   // 0..7 within 8-row chunk
  const int vcol_l = ((lane & 7) * 8) ^ ((vrow_l & 7) << 3);  // vr&7==vrow_l

  // Q fragments: 8 k-chunks (sig, 1/sqrt(hd), log2e pre-folded)
  u16x8 qf[8];
#pragma unroll
  for (int c = 0; c < 8; ++c)
    qf[c] = *(const u16x8*)&qb[(size_t)(b * S_DIM + q0 + lr) * F_DIM +
                               h * HD + c * 32 + hi * 8];

  float mrow[4], lacc[4];
#pragma unroll
  for (int r = 0; r < 4; ++r) { mrow[r] = -1e30f; lacc[r] = 0.0f; }
  f32x4 oacc[16];
#pragma unroll
  for (int d = 0; d < 16; ++d) oacc[d] = (f32x4)0.0f;

  const u16* kbase = kb + (size_t)b * S_DIM * F_DIM + h * HD;
  const u16* vbase = vt + ((size_t)b * F_DIM + h * HD) * S_DIM;

  // ---- stage tile 0 into buffer 0 (4 K-chunks + 4 V-chunks per wave)
#pragma unroll
  for (int i = 0; i < 4; ++i) {
    int ck = wid * 4 + i;
    int kr = ck * 2 + krow_l;
    gload16(kbase + (size_t)kr * F_DIM + (kcolb ^ ((kr & 7) << 3)),
            &Kbuf[0][ck * 512]);
    int vr = ck * 8 + vrow_l;
    gload16(vbase + (size_t)vr * S_DIM + vcol_l, &Vbuf[0][ck * 512]);
  }
  __syncthreads();   // compiler emits vmcnt(0) drain here

  for (int t = 0; t < 32; ++t) {
    const int cur = t & 1;
    // ---- issue next tile's loads into the other buffer (async)
    if (t < 31) {
      int kv1 = (t + 1) * 64;
#pragma unroll
      for (int i = 0; i < 4; ++i) {
        int ck = wid * 4 + i;
        int kr = ck * 2 + krow_l;
        gload16(kbase + (size_t)(kv1 + kr) * F_DIM + (kcolb ^ ((kr & 7) << 3)),
                &Kbuf[cur ^ 1][ck * 512]);
        int vr = ck * 8 + vrow_l;
        gload16(vbase + (size_t)vr * S_DIM + kv1 + vcol_l,
                &Vbuf[cur ^ 1][ck * 512]);
      }
    }

    // ---- S = Q . K^T : 16 rows x 64 cols (4 col-frags)
    f32x4 sacc[4];
#pragma unroll
    for (int n = 0; n < 4; ++n) sacc[n] = (f32x4)0.0f;
#pragma unroll
    for (int c = 0; c < 8; ++c) {
      s16x8 a = *(const s16x8*)&qf[c];
#pragma unroll
      for (int n = 0; n < 4; ++n) {
        s16x8 kf = *(const s16x8*)&Kbuf[cur][(n * 16 + lr) * 256 +
                                             ((c * 32 + hi * 8) ^ lr7s)];
        sacc[n] = mfma16(a, kf, sacc[n]);
      }
    }

    // ---- online softmax (log2 domain); rows = hi*4 + r
    float pmax[4], need = 0.0f;
#pragma unroll
    for (int r = 0; r < 4; ++r) {
      float mx = fmaxf(fmaxf(sacc[0][r], sacc[1][r]),
                       fmaxf(sacc[2][r], sacc[3][r]));
      mx = fmaxf(mx, __shfl_xor(mx, 1));
      mx = fmaxf(mx, __shfl_xor(mx, 2));
      mx = fmaxf(mx, __shfl_xor(mx, 4));
      mx = fmaxf(mx, __shfl_xor(mx, 8));
      pmax[r] = mx;
      need = fmaxf(need, mx - mrow[r]);
    }
    if (!__all(need <= 8.0f)) {
#pragma unroll
      for (int r = 0; r < 4; ++r) {
        float mnew = fmaxf(mrow[r], pmax[r]);
        float alpha = exp2f(mrow[r] - mnew);
        mrow[r] = mnew;
        lacc[r] *= alpha;
#pragma unroll
        for (int d = 0; d < 16; ++d) oacc[d][r] *= alpha;
      }
    }
#pragma unroll
    for (int n = 0; n < 4; ++n)
#pragma unroll
      for (int r = 0; r < 4; ++r) {
        float p = exp2f(sacc[n][r] - mrow[r]);
        lacc[r] += p;
        Ps[wid][hi * 4 + r][n * 16 + lr] = f2bf(p);
      }

    // ---- O += P . V  (per-wave LDS round-trip for P; V swizzled reads)
#pragma unroll
    for (int ks = 0; ks < 2; ++ks) {
      s16x8 pf = *(const s16x8*)&Ps[wid][lr][ks * 32 + hi * 8];
#pragma unroll
      for (int d0 = 0; d0 < 16; ++d0) {
        s16x8 vf = *(const s16x8*)&Vbuf[cur][(d0 * 16 + lr) * 64 +
                                             ((ks * 32 + hi * 8) ^ lr7s)];
        oacc[d0] = mfma16(pf, vf, oacc[d0]);
      }
    }
    __syncthreads();   // drains this wave's prefetch (vmcnt 0) + buf swap
  }

  // ---- epilogue: reduce distributed row-sums, divide, write bf16
#pragma unroll
  for (int r = 0; r < 4; ++r) {
    float s = lacc[r];
    s += __shfl_xor(s, 1);
    s += __shfl_xor(s, 2);
    s += __shfl_xor(s, 4);
    s += __shfl_xor(s, 8);
    float inv = 1.0f / s;
    int row = q0 + hi * 4 + r;
#pragma unroll
    for (int d0 = 0; d0 < 16; ++d0)
      ao[(size_t)(b * S_DIM + row) * F_DIM + h * HD + d0 * 16 + lr] =
          f2bf(oacc[d0][r] * inv);
  }
}

// ---------------------------------------------------------------------------
extern "C" void kernel_launch(void* const* d_in, const int* in_sizes, int n_in,
                              void* d_out, int out_size, void* d_ws, size_t ws_size,
                              hipStream_t stream) {
  const float* x  = (const float*)d_in[0];
  const float* wq = (const float*)d_in[1];
  const float* wk = (const float*)d_in[2];
  const float* wv = (const float*)d_in[3];
  const float* wo = (const float*)d_in[4];

  char* ws = (char*)d_ws;
  const size_t SZ_XB = (size_t)TOK * F_DIM * sizeof(u16);    // 16 MiB
  const size_t SZ_W  = (size_t)F_DIM * F_DIM * sizeof(u16);  // 8 MiB
  u16* Xb = (u16*)(ws);
  u16* Wb = (u16*)(ws + SZ_XB);            // reused per projection
  u16* Qb = (u16*)(ws + SZ_XB + SZ_W);
  u16* Kb = Qb + (size_t)TOK * F_DIM;
  u16* Vt = Kb + (size_t)TOK * F_DIM;      // V, normalized + transposed
  u16* Ao = Xb;                            // aliases Xb (dead after V GEMM)

  dim3 gemm_grid(F_DIM / 128, TOK / 128);  // (16, 32)
  const int bw_blocks = D_DIM * D_DIM;

  k_cast<<<TOK * F_DIM / (256 * 8), 256, 0, stream>>>(x, Xb);

  k_buildw<<<bw_blocks, 256, 0, stream>>>(wq, Wb);
  k_gemm_fused<1><<<gemm_grid, 256, 0, stream>>>(Xb, Wb, Qb, nullptr);

  k_buildw<<<bw_blocks, 256, 0, stream>>>(wk, Wb);
  k_gemm_fused<0><<<gemm_grid, 256, 0, stream>>>(Xb, Wb, Kb, nullptr);

  k_buildw<<<bw_blocks, 256, 0, stream>>>(wv, Wb);
  k_gemm_fused<3><<<gemm_grid, 256, 0, stream>>>(Xb, Wb, Vt, nullptr);

  k_attn<<<B_DIM * NH * (S_DIM / 128), 512, 0, stream>>>(Qb, Kb, Vt, Ao);

  k_buildw<<<bw_blocks, 256, 0, stream>>>(wo, Wb);
  k_gemm_fused<2><<<gemm_grid, 256, 0, stream>>>(Ao, Wb, nullptr, (float*)d_out);
}

// Round 9
// 443.273 us; speedup vs baseline: 1.2148x; 1.0017x over previous
//
#include <hip/hip_runtime.h>
#include <hip/hip_bf16.h>

// ---------------------------------------------------------------------------
// VersorAttention on MI355X (gfx950).
// cast x->bf16; buildW x3 -> ONE fused QKV GEMM (N=6144, region-branched
// epilogue: Q sig*scale*log2e, K plain, V transposed into d_out scratch);
// flash attention v4 (8 waves x 16 q-rows, 2 waves/SIMD, KV=64 dbuf via
// global_load_lds + XOR swizzle, one barrier/tile, defer-max, exp2);
// buildW(wo) -> final GEMM + fused fp32 normalize -> d_out.
// ---------------------------------------------------------------------------

typedef unsigned short u16;
typedef unsigned short u16x8 __attribute__((ext_vector_type(8)));
typedef unsigned short u16x4 __attribute__((ext_vector_type(4)));
typedef short          s16x8 __attribute__((ext_vector_type(8)));
typedef float          f32x4 __attribute__((ext_vector_type(4)));

#define B_DIM 2
#define S_DIM 2048
#define D_DIM 64
#define NH    8
#define HD    256          // head feature = (D/NH)*32
#define F_DIM 2048         // D*32
#define TOK   4096         // B*S

// blade lane ordering: sorted by (grade, mask)
__constant__ int LANE_MASK[32] = {
    0,
    1, 2, 4, 8, 16,
    3, 5, 6, 9, 10, 12, 17, 18, 20, 24,
    7, 11, 13, 14, 19, 21, 22, 25, 26, 28,
    15, 23, 27, 29, 30,
    31};
__constant__ int MASK_LANE[32] = {
    0, 1, 2, 6, 3, 7, 8, 16, 4, 9, 10, 17, 11, 18, 19, 26,
    5, 12, 13, 20, 14, 21, 22, 27, 15, 23, 24, 28, 25, 29, 30, 31};

__device__ __forceinline__ float gp_sign(int a, int b) {
  int swaps = 0;
  int aa = a >> 1;
  while (aa) { swaps += __popc(aa & b); aa >>= 1; }
  float s = (swaps & 1) ? -1.0f : 1.0f;
  if (a & b & 16) s = -s;   // e5*e5 = -1 (bit 4); e1..e4 square to +1
  return s;
}

__device__ __forceinline__ u16 f2bf(float f) {
  unsigned u = __float_as_uint(f);
  u += 0x7fffu + ((u >> 16) & 1u);   // round-to-nearest-even
  return (u16)(u >> 16);
}

__device__ __forceinline__ f32x4 mfma16(s16x8 a, s16x8 b, f32x4 c) {
  return __builtin_amdgcn_mfma_f32_16x16x32_bf16(a, b, c, 0, 0, 0);
}

// async global->LDS, 16B per lane; LDS dest = wave-uniform base + lane*16
__device__ __forceinline__ void gload16(const u16* g, u16* l) {
  __builtin_amdgcn_global_load_lds(
      (const __attribute__((address_space(1))) void*)g,
      (__attribute__((address_space(3))) void*)l, 16, 0, 0);
}

// ---------------------------------------------------------------------------
// x (fp32) -> bf16
__global__ __launch_bounds__(256) void k_cast(const float* __restrict__ x,
                                              u16* __restrict__ xb) {
  int i = blockIdx.x * 256 + threadIdx.x;   // 8 elements each
  const float4* x4 = (const float4*)x;
  float4 a = x4[2 * i], b = x4[2 * i + 1];
  u16x8 r;
  r[0] = f2bf(a.x); r[1] = f2bf(a.y); r[2] = f2bf(a.z); r[3] = f2bf(a.w);
  r[4] = f2bf(b.x); r[5] = f2bf(b.y); r[6] = f2bf(b.z); r[7] = f2bf(b.w);
  *(u16x8*)&xb[8 * i] = r;
}

// ---------------------------------------------------------------------------
// W[(o*32+k)*2048 + i*32+l] = gp_sign(mask_k^mask_l, mask_l) * w[o,i,j],
// mask_j = mask_k ^ mask_l  (gp table one-hot in output blade).
__global__ __launch_bounds__(256) void k_buildw(const float* __restrict__ w,
                                                u16* __restrict__ W) {
  __shared__ float wvals[32];
  __shared__ int   jt[1024];
  __shared__ float st[1024];
  const int o = blockIdx.x >> 6, i = blockIdx.x & 63;
  const int tid = threadIdx.x;
  for (int e = tid; e < 1024; e += 256) {
    int k = e >> 5, l = e & 31;
    int mk = LANE_MASK[k], ml = LANE_MASK[l];
    int mj = mk ^ ml;
    jt[e] = MASK_LANE[mj];
    st[e] = gp_sign(mj, ml);
  }
  if (tid < 32) wvals[tid] = w[(o * D_DIM + i) * 32 + tid];
  __syncthreads();
  for (int e = tid; e < 1024; e += 256) {
    int k = e >> 5, l = e & 31;
    size_t off = (size_t)(o * 32 + k) * F_DIM + i * 32 + l;
    W[off] = f2bf(st[e] * wvals[jt[e]]);
  }
}

// ---------------------------------------------------------------------------
// Fused QKV GEMM: C(4096 x 6144) = Xb(4096x2048) . Wcat(6144x2048)^T with
// per-region fused normalize epilogue.  Region = blockIdx.x>>4 (block-uniform):
//   0: Qb = norm * sig*scale*log2e   1: Kb = norm   2: Vt[b][f][s] = norm^T
// m97 structure: 128x128 tile, BK=64, linear LDS, global_load_lds width=16.
// grid (48,32) = 1536 blocks = 6/CU -> cross-block barrier-drain hiding.
__global__ __launch_bounds__(256) void k_gemm_qkv(const u16* __restrict__ A,
                                                  const u16* __restrict__ Wcat,
                                                  u16* __restrict__ Qb,
                                                  u16* __restrict__ Kb,
                                                  u16* __restrict__ Vt) {
  constexpr int K = F_DIM;
  __shared__ u16 As[128 * 64];
  __shared__ u16 Bs[128 * 64];
  const int tid = threadIdx.x;
  const int wid = tid >> 6, lane = tid & 63;
  const int region = blockIdx.x >> 4;            // 0=Q 1=K 2=V
  const int col0 = (blockIdx.x & 15) * 128;      // within region [0,2048)
  const int row0 = blockIdx.y * 128;
  const u16* Bsrc = Wcat + (size_t)region * F_DIM * F_DIM;
  const int wm = (wid >> 1) * 64, wn = (wid & 1) * 64;
  const int lr = lane & 15, lk = (lane >> 4) * 8;
  const int srow = lane >> 3, scol = (lane & 7) * 8;   // staging: 8 rows/wave

  f32x4 acc[4][4];
#pragma unroll
  for (int m = 0; m < 4; ++m)
#pragma unroll
    for (int n = 0; n < 4; ++n) acc[m][n] = (f32x4)0.0f;

  for (int k0 = 0; k0 < K; k0 += 64) {
#pragma unroll
    for (int it = 0; it < 4; ++it) {
      int c = it * 4 + wid;            // 16 chunks of 8 rows x 64 cols
      gload16(&A[(size_t)(row0 + c * 8 + srow) * K + k0 + scol], &As[c * 512]);
      gload16(&Bsrc[(size_t)(col0 + c * 8 + srow) * K + k0 + scol], &Bs[c * 512]);
    }
    __syncthreads();
#pragma unroll
    for (int ks = 0; ks < 64; ks += 32) {
      s16x8 af[4], bf[4];
#pragma unroll
      for (int m = 0; m < 4; ++m)
        af[m] = *(const s16x8*)&As[(wm + m * 16 + lr) * 64 + ks + lk];
#pragma unroll
      for (int n = 0; n < 4; ++n)
        bf[n] = *(const s16x8*)&Bs[(wn + n * 16 + lr) * 64 + ks + lk];
#pragma unroll
      for (int m = 0; m < 4; ++m)
#pragma unroll
        for (int n = 0; n < 4; ++n)
          acc[m][n] = mfma16(af[m], bf[n], acc[m][n]);
    }
    __syncthreads();
  }

  // epilogue: per-multivector normalize (cols [c32,c32+32) of each row)
  float sc0 = 1.0f, sc1 = 1.0f;
  if (region == 0) {
    const float qs = 0.35355339059327373f * 1.4426950408889634f;  // 1/sqrt(8)*log2e
    int m0 = LANE_MASK[lr], m1 = LANE_MASK[16 + lr];
    sc0 = gp_sign(m0, m0) * qs;
    sc1 = gp_sign(m1, m1) * qs;
  }
#pragma unroll
  for (int m = 0; m < 4; ++m) {
    int rowb = row0 + wm + m * 16 + (lane >> 4) * 4;
#pragma unroll
    for (int np = 0; np < 2; ++np) {
      int n0 = 2 * np, n1 = n0 + 1;
      int colb = col0 + wn + np * 32 + lr;
      f32x4 inv;
#pragma unroll
      for (int r = 0; r < 4; ++r) {
        float a0 = acc[m][n0][r], a1 = acc[m][n1][r];
        float s2 = a0 * a0 + a1 * a1;
        s2 += __shfl_xor(s2, 1);
        s2 += __shfl_xor(s2, 2);
        s2 += __shfl_xor(s2, 4);
        s2 += __shfl_xor(s2, 8);
        inv[r] = 1.0f / sqrtf(s2 + 1e-6f);
      }
      if (region == 2) {
        // V: write normalized, transposed: Vt[(b*F + f)*S + s]
        int bb = rowb >> 11, s0 = rowb & 2047;
        u16x4 p0, p1;
#pragma unroll
        for (int r = 0; r < 4; ++r) {
          p0[r] = f2bf(acc[m][n0][r] * inv[r]);
          p1[r] = f2bf(acc[m][n1][r] * inv[r]);
        }
        *(u16x4*)&Vt[((size_t)bb * F_DIM + colb) * S_DIM + s0] = p0;
        *(u16x4*)&Vt[((size_t)bb * F_DIM + colb + 16) * S_DIM + s0] = p1;
      } else {
        u16* dst = (region == 0) ? Qb : Kb;
#pragma unroll
        for (int r = 0; r < 4; ++r) {
          size_t o = (size_t)(rowb + r) * F_DIM + colb;
          dst[o]      = f2bf(acc[m][n0][r] * inv[r] * sc0);
          dst[o + 16] = f2bf(acc[m][n1][r] * inv[r] * sc1);
        }
      }
    }
  }
}

// ---------------------------------------------------------------------------
// Final GEMM: C = Ao . Wo^T with fused fp32 normalize -> d_out.
__global__ __launch_bounds__(256) void k_gemm_fin(const u16* __restrict__ A,
                                                  const u16* __restrict__ B,
                                                  float* __restrict__ outf) {
  constexpr int K = F_DIM, N = F_DIM;
  __shared__ u16 As[128 * 64];
  __shared__ u16 Bs[128 * 64];
  const int tid = threadIdx.x;
  const int wid = tid >> 6, lane = tid & 63;
  const int row0 = blockIdx.y * 128, col0 = blockIdx.x * 128;
  const int wm = (wid >> 1) * 64, wn = (wid & 1) * 64;
  const int lr = lane & 15, lk = (lane >> 4) * 8;
  const int srow = lane >> 3, scol = (lane & 7) * 8;

  f32x4 acc[4][4];
#pragma unroll
  for (int m = 0; m < 4; ++m)
#pragma unroll
    for (int n = 0; n < 4; ++n) acc[m][n] = (f32x4)0.0f;

  for (int k0 = 0; k0 < K; k0 += 64) {
#pragma unroll
    for (int it = 0; it < 4; ++it) {
      int c = it * 4 + wid;
      gload16(&A[(size_t)(row0 + c * 8 + srow) * K + k0 + scol], &As[c * 512]);
      gload16(&B[(size_t)(col0 + c * 8 + srow) * K + k0 + scol], &Bs[c * 512]);
    }
    __syncthreads();
#pragma unroll
    for (int ks = 0; ks < 64; ks += 32) {
      s16x8 af[4], bf[4];
#pragma unroll
      for (int m = 0; m < 4; ++m)
        af[m] = *(const s16x8*)&As[(wm + m * 16 + lr) * 64 + ks + lk];
#pragma unroll
      for (int n = 0; n < 4; ++n)
        bf[n] = *(const s16x8*)&Bs[(wn + n * 16 + lr) * 64 + ks + lk];
#pragma unroll
      for (int m = 0; m < 4; ++m)
#pragma unroll
        for (int n = 0; n < 4; ++n)
          acc[m][n] = mfma16(af[m], bf[n], acc[m][n]);
    }
    __syncthreads();
  }

#pragma unroll
  for (int m = 0; m < 4; ++m) {
    int rowb = row0 + wm + m * 16 + (lane >> 4) * 4;
#pragma unroll
    for (int np = 0; np < 2; ++np) {
      int n0 = 2 * np, n1 = n0 + 1;
      int colb = col0 + wn + np * 32 + lr;
#pragma unroll
      for (int r = 0; r < 4; ++r) {
        float a0 = acc[m][n0][r], a1 = acc[m][n1][r];
        float s2 = a0 * a0 + a1 * a1;
        s2 += __shfl_xor(s2, 1);
        s2 += __shfl_xor(s2, 2);
        s2 += __shfl_xor(s2, 4);
        s2 += __shfl_xor(s2, 8);
        float inv = 1.0f / sqrtf(s2 + 1e-6f);
        size_t o = (size_t)(rowb + r) * N + colb;
        outf[o]      = a0 * inv;
        outf[o + 16] = a1 * inv;
      }
    }
  }
}

// ---------------------------------------------------------------------------
// Flash attention v4.  512 threads = 8 waves x 16 q-rows (q-tile 128);
// grid 256 = 1 block/CU but 2 waves/SIMD -> cross-wave MFMA/VALU overlap.
// KV=64 double-buffered via global_load_lds, XOR swizzle (stage side uses
// absolute row: kr&7 / vr&7; read side lr&7 -- rule #21 both-sides).
// ONE barrier per tile.  Scores in log2 domain; defer-max THR=8.
__global__ __launch_bounds__(512, 2) void k_attn(const u16* __restrict__ qb,
                                                 const u16* __restrict__ kb,
                                                 const u16* __restrict__ vt,
                                                 u16* __restrict__ ao) {
  __shared__ u16 Kbuf[2][64 * 256];   // [kv][feat], swizzled, 2x32 KB
  __shared__ u16 Vbuf[2][256 * 64];   // [feat][kv], swizzled, 2x32 KB
  __shared__ u16 Ps[8][16][72];       // per-wave P, padded pitch (18 KB)
  const int tid = threadIdx.x, wid = tid >> 6, lane = tid & 63;
  // XCD remap: 2 (b,h) pairs per XCD -> K+V (4 MB) resident in one L2
  const int rid = (blockIdx.x & 7) * 32 + (blockIdx.x >> 3);
  const int qblk = rid & 15, bh = rid >> 4;
  const int b = bh >> 3, h = bh & 7;
  const int lr = lane & 15, hi = lane >> 4;      // frag row / k-group
  const int lr7s = (lr & 7) << 3;                // read-side XOR (u16 units)
  const int q0 = qblk * 128 + wid * 16;

  // staging geometry: 32 K-chunks + 32 V-chunks of 1 KB, 4+4 per wave
  const int krow_l = lane >> 5;                   // 0..1 within 2-row chunk
  const int kcolb  = (lane & 31) * 8;             // linear dest col (u16)
  const int vrow_l = lane >> 3;                   // 0..7 within 8-row chunk
  const int vcol_l = ((lane & 7) * 8) ^ ((vrow_l & 7) << 3);  // vr&7==vrow_l

  // Q fragments: 8 k-chunks (sig, 1/sqrt(hd), log2e pre-folded)
  u16x8 qf[8];
#pragma unroll
  for (int c = 0; c < 8; ++c)
    qf[c] = *(const u16x8*)&qb[(size_t)(b * S_DIM + q0 + lr) * F_DIM +
                               h * HD + c * 32 + hi * 8];

  float mrow[4], lacc[4];
#pragma unroll
  for (int r = 0; r < 4; ++r) { mrow[r] = -1e30f; lacc[r] = 0.0f; }
  f32x4 oacc[16];
#pragma unroll
  for (int d = 0; d < 16; ++d) oacc[d] = (f32x4)0.0f;

  const u16* kbase = kb + (size_t)b * S_DIM * F_DIM + h * HD;
  const u16* vbase = vt + ((size_t)b * F_DIM + h * HD) * S_DIM;

  // ---- stage tile 0 into buffer 0 (4 K-chunks + 4 V-chunks per wave)
#pragma unroll
  for (int i = 0; i < 4; ++i) {
    int ck = wid * 4 + i;
    int kr = ck * 2 + krow_l;
    gload16(kbase + (size_t)kr * F_DIM + (kcolb ^ ((kr & 7) << 3)),
            &Kbuf[0][ck * 512]);
    int vr = ck * 8 + vrow_l;
    gload16(vbase + (size_t)vr * S_DIM + vcol_l, &Vbuf[0][ck * 512]);
  }
  __syncthreads();   // compiler emits vmcnt(0) drain here

  for (int t = 0; t < 32; ++t) {
    const int cur = t & 1;
    // ---- issue next tile's loads into the other buffer (async)
    if (t < 31) {
      int kv1 = (t + 1) * 64;
#pragma unroll
      for (int i = 0; i < 4; ++i) {
        int ck = wid * 4 + i;
        int kr = ck * 2 + krow_l;
        gload16(kbase + (size_t)(kv1 + kr) * F_DIM + (kcolb ^ ((kr & 7) << 3)),
                &Kbuf[cur ^ 1][ck * 512]);
        int vr = ck * 8 + vrow_l;
        gload16(vbase + (size_t)vr * S_DIM + kv1 + vcol_l,
                &Vbuf[cur ^ 1][ck * 512]);
      }
    }

    // ---- S = Q . K^T : 16 rows x 64 cols (4 col-frags)
    f32x4 sacc[4];
#pragma unroll
    for (int n = 0; n < 4; ++n) sacc[n] = (f32x4)0.0f;
#pragma unroll
    for (int c = 0; c < 8; ++c) {
      s16x8 a = *(const s16x8*)&qf[c];
#pragma unroll
      for (int n = 0; n < 4; ++n) {
        s16x8 kf = *(const s16x8*)&Kbuf[cur][(n * 16 + lr) * 256 +
                                             ((c * 32 + hi * 8) ^ lr7s)];
        sacc[n] = mfma16(a, kf, sacc[n]);
      }
    }

    // ---- online softmax (log2 domain); rows = hi*4 + r
    float pmax[4], need = 0.0f;
#pragma unroll
    for (int r = 0; r < 4; ++r) {
      float mx = fmaxf(fmaxf(sacc[0][r], sacc[1][r]),
                       fmaxf(sacc[2][r], sacc[3][r]));
      mx = fmaxf(mx, __shfl_xor(mx, 1));
      mx = fmaxf(mx, __shfl_xor(mx, 2));
      mx = fmaxf(mx, __shfl_xor(mx, 4));
      mx = fmaxf(mx, __shfl_xor(mx, 8));
      pmax[r] = mx;
      need = fmaxf(need, mx - mrow[r]);
    }
    if (!__all(need <= 8.0f)) {
#pragma unroll
      for (int r = 0; r < 4; ++r) {
        float mnew = fmaxf(mrow[r], pmax[r]);
        float alpha = exp2f(mrow[r] - mnew);
        mrow[r] = mnew;
        lacc[r] *= alpha;
#pragma unroll
        for (int d = 0; d < 16; ++d) oacc[d][r] *= alpha;
      }
    }
#pragma unroll
    for (int n = 0; n < 4; ++n)
#pragma unroll
      for (int r = 0; r < 4; ++r) {
        float p = exp2f(sacc[n][r] - mrow[r]);
        lacc[r] += p;
        Ps[wid][hi * 4 + r][n * 16 + lr] = f2bf(p);
      }

    // ---- O += P . V  (per-wave LDS round-trip for P; V swizzled reads)
#pragma unroll
    for (int ks = 0; ks < 2; ++ks) {
      s16x8 pf = *(const s16x8*)&Ps[wid][lr][ks * 32 + hi * 8];
#pragma unroll
      for (int d0 = 0; d0 < 16; ++d0) {
        s16x8 vf = *(const s16x8*)&Vbuf[cur][(d0 * 16 + lr) * 64 +
                                             ((ks * 32 + hi * 8) ^ lr7s)];
        oacc[d0] = mfma16(pf, vf, oacc[d0]);
      }
    }
    __syncthreads();   // drains this wave's prefetch (vmcnt 0) + buf swap
  }

  // ---- epilogue: reduce distributed row-sums, divide, write bf16
#pragma unroll
  for (int r = 0; r < 4; ++r) {
    float s = lacc[r];
    s += __shfl_xor(s, 1);
    s += __shfl_xor(s, 2);
    s += __shfl_xor(s, 4);
    s += __shfl_xor(s, 8);
    float inv = 1.0f / s;
    int row = q0 + hi * 4 + r;
#pragma unroll
    for (int d0 = 0; d0 < 16; ++d0)
      ao[(size_t)(b * S_DIM + row) * F_DIM + h * HD + d0 * 16 + lr] =
          f2bf(oacc[d0][r] * inv);
  }
}

// ---------------------------------------------------------------------------
extern "C" void kernel_launch(void* const* d_in, const int* in_sizes, int n_in,
                              void* d_out, int out_size, void* d_ws, size_t ws_size,
                              hipStream_t stream) {
  const float* x  = (const float*)d_in[0];
  const float* wq = (const float*)d_in[1];
  const float* wk = (const float*)d_in[2];
  const float* wv = (const float*)d_in[3];
  const float* wo = (const float*)d_in[4];

  char* ws = (char*)d_ws;
  const size_t SZ_XB = (size_t)TOK * F_DIM * sizeof(u16);    // 16 MiB
  const size_t SZ_W  = (size_t)F_DIM * F_DIM * sizeof(u16);  // 8 MiB
  u16* Xb   = (u16*)(ws);
  u16* Wcat = (u16*)(ws + SZ_XB);           // 3x8 MiB (Wq,Wk,Wv; Wo reuses [0])
  u16* Qb   = (u16*)(ws + SZ_XB + 3 * SZ_W);
  u16* Kb   = Qb + (size_t)TOK * F_DIM;
  u16* Vt   = (u16*)d_out;                  // first 16 MiB of d_out (32 MiB);
                                            // overwritten by final GEMM later
  u16* Ao   = Xb;                           // aliases Xb (dead after QKV GEMM)

  const int bw_blocks = D_DIM * D_DIM;

  k_cast<<<TOK * F_DIM / (256 * 8), 256, 0, stream>>>(x, Xb);

  k_buildw<<<bw_blocks, 256, 0, stream>>>(wq, Wcat);
  k_buildw<<<bw_blocks, 256, 0, stream>>>(wk, Wcat + (size_t)F_DIM * F_DIM);
  k_buildw<<<bw_blocks, 256, 0, stream>>>(wv, Wcat + 2 * (size_t)F_DIM * F_DIM);

  k_gemm_qkv<<<dim3(48, 32), 256, 0, stream>>>(Xb, Wcat, Qb, Kb, Vt);

  k_attn<<<B_DIM * NH * (S_DIM / 128), 512, 0, stream>>>(Qb, Kb, Vt, Ao);

  k_buildw<<<bw_blocks, 256, 0, stream>>>(wo, Wcat);
  k_gemm_fin<<<dim3(16, 32), 256, 0, stream>>>(Ao, Wcat, (float*)d_out);
}